// Round 2
// baseline (7246.864 us; speedup 1.0000x reference)
//
#include <hip/hip_runtime.h>
#include <math.h>

typedef unsigned short u16;
typedef short bf16x8 __attribute__((ext_vector_type(8)));
typedef float f32x4 __attribute__((ext_vector_type(4)));

__device__ __forceinline__ float bf2f(u16 h) {
    union { unsigned u; float f; } v; v.u = ((unsigned)h) << 16; return v.f;
}
__device__ __forceinline__ u16 f2bf(float f) {
    union { float f; unsigned u; } v; v.f = f;
    unsigned r = v.u + 0x7fffu + ((v.u >> 16) & 1u);
    return (u16)(r >> 16);
}

#define CH    512
#define NPIX  16384
#define PTOT  32768
#define NHEAD 8

// ---------------- fp32 transpose [R][Cc] -> [Cc][R] per z slab ----------------
__global__ void transpose_k(const float* __restrict__ in, float* outF, u16* outB,
                            int R, int Cc, size_t ibs, size_t obs)
{
    __shared__ float tile[32][33];
    int z = blockIdx.z;
    const float* ip = in + (size_t)z * ibs;
    int c0 = blockIdx.x * 32, r0 = blockIdx.y * 32;
    int tx = threadIdx.x, ty = threadIdx.y;
#pragma unroll
    for (int j = 0; j < 4; j++)
        tile[ty + j * 8][tx] = ip[(size_t)(r0 + ty + j * 8) * Cc + c0 + tx];
    __syncthreads();
#pragma unroll
    for (int j = 0; j < 4; j++) {
        int orow = c0 + ty + j * 8, ocol = r0 + tx;
        float v = tile[tx][ty + j * 8];
        size_t o = (size_t)z * obs + (size_t)orow * R + ocol;
        if (outF) outF[o] = v;
        if (outB) outB[o] = f2bf(v);
    }
}

// ---------------- bf16 transpose [R][Cc] -> [Cc][R] per z slab ----------------
__global__ void transpose16_k(const u16* __restrict__ in, u16* __restrict__ out,
                              int R, int Cc, size_t ibs, size_t obs)
{
    __shared__ u16 tile[32][34];
    int z = blockIdx.z;
    const u16* ip = in + (size_t)z * ibs;
    int c0 = blockIdx.x * 32, r0 = blockIdx.y * 32;
    int tx = threadIdx.x, ty = threadIdx.y;
#pragma unroll
    for (int j = 0; j < 4; j++)
        tile[ty + j * 8][tx] = ip[(size_t)(r0 + ty + j * 8) * Cc + c0 + tx];
    __syncthreads();
#pragma unroll
    for (int j = 0; j < 4; j++)
        out[(size_t)z * obs + (size_t)(c0 + ty + j * 8) * R + r0 + tx] = tile[tx][ty + j * 8];
}

// ---------------- fp32 -> bf16 convert (4 elems/thread) ----------------
__global__ void cvt_bf16_k(const float* __restrict__ in, u16* __restrict__ out)
{
    size_t i = ((size_t)blockIdx.x * 256 + threadIdx.x) * 4;
    float4 v = *(const float4*)&in[i];
    uint2 st;
    st.x = (unsigned)f2bf(v.x) | ((unsigned)f2bf(v.y) << 16);
    st.y = (unsigned)f2bf(v.z) | ((unsigned)f2bf(v.w) << 16);
    *(uint2*)&out[i] = st;
}

// ---------------- bf16 NT GEMM: out[i,o] = sum_k A[i,k]*B[o,k] ----------------
// 128x128 tile, BK=32, 256 thr, 16x16x32 MFMA. Optional split-K partials via
// blockIdx.z (kChunk>0 -> write fp32 partial slabs). ldb = B row stride.
__global__ __launch_bounds__(256) void gemm_nt_k(
    const u16* __restrict__ A, const u16* __restrict__ Bw,
    int K, int ldb, int Nn, int rowsPerBatch, int bStride, int kChunk,
    const float* __restrict__ bias, const float* resid,
    float* outF, u16* outB)
{
    __shared__ u16 As[128 * 32];
    __shared__ u16 Bs[128 * 32];
    int tid = threadIdx.x;
    int rowBase = blockIdx.y * 128, colBase = blockIdx.x * 128;
    const u16* Bp = Bw + (size_t)(rowBase / rowsPerBatch) * bStride;

    int kb = 0, ke = K;
    float* outFp = outF;
    if (kChunk) {
        kb = blockIdx.z * kChunk; ke = kb + kChunk;
        outFp = outF + (size_t)blockIdx.z * (size_t)gridDim.y * 128 * Nn;
    }

    f32x4 acc[4][4] = {};
    int lane = tid & 63, wave = tid >> 6;
    int wr = wave >> 1, wc = wave & 1;
    int lm = lane & 15, lk = lane >> 4;

    for (int k0 = kb; k0 < ke; k0 += 32) {
        __syncthreads();
#pragma unroll
        for (int j = 0; j < 2; j++) {
            int ch = j * 256 + tid;
            int row = ch >> 2, kc = (ch & 3) * 8;
            *(uint4*)&As[row * 32 + kc] =
                *(const uint4*)&A[(size_t)(rowBase + row) * K + k0 + kc];
            *(uint4*)&Bs[row * 32 + kc] =
                *(const uint4*)&Bp[(size_t)(colBase + row) * ldb + k0 + kc];
        }
        __syncthreads();
        bf16x8 af[4], bfr[4];
#pragma unroll
        for (int mt = 0; mt < 4; mt++)
            af[mt] = *(const bf16x8*)&As[(wr * 64 + mt * 16 + lm) * 32 + lk * 8];
#pragma unroll
        for (int nt = 0; nt < 4; nt++)
            bfr[nt] = *(const bf16x8*)&Bs[(wc * 64 + nt * 16 + lm) * 32 + lk * 8];
#pragma unroll
        for (int mt = 0; mt < 4; mt++)
#pragma unroll
            for (int nt = 0; nt < 4; nt++)
                acc[mt][nt] = __builtin_amdgcn_mfma_f32_16x16x32_bf16(
                    af[mt], bfr[nt], acc[mt][nt], 0, 0, 0);
    }

#pragma unroll
    for (int mt = 0; mt < 4; mt++)
#pragma unroll
        for (int nt = 0; nt < 4; nt++) {
            int col = colBase + wc * 64 + nt * 16 + lm;
            float bv = bias ? bias[col] : 0.f;
#pragma unroll
            for (int r = 0; r < 4; r++) {
                int row = rowBase + wr * 64 + mt * 16 + lk * 4 + r;
                size_t o = (size_t)row * Nn + col;
                float v = acc[mt][nt][r] + bv;
                if (resid) v += resid[o];
                if (outFp) outFp[o] = v;
                if (outB) outB[o] = f2bf(v);
            }
        }
}

// ---------------- reduce 8 split-K partials -> bf16 ----------------
__global__ void sreduce_k(const float* __restrict__ Sp, u16* __restrict__ Sbf)
{
    int i = blockIdx.x * 256 + threadIdx.x;
    float s = 0.f;
#pragma unroll
    for (int z = 0; z < 8; z++) s += Sp[(size_t)z * 524288 + i];
    Sbf[i] = f2bf(s);
}

// ---------------- inv l2 norms: inv[b,e] = 1/max(sqrt(sum_c w[c,e]*Tf[b,c,e]),eps) ---
__global__ void nrm_k(const float* __restrict__ w, const float* __restrict__ Tf,
                      float* __restrict__ inv)
{
    int idx = blockIdx.x * 256 + threadIdx.x;   // 0..2047
    int e = idx & 511, b = idx >> 9;
    float s = 0.f;
    for (int c = 0; c < 512; c++)
        s += w[c * 512 + e] * Tf[(size_t)(b * 512 + c) * 512 + e];
    s = fmaxf(s, 0.f);
    inv[b * 512 + e] = 1.f / fmaxf(sqrtf(s), 1e-12f);
}

// ---------------- G[b,h,d,e]=sum_c T2[b,c,h64+d]*Wq[c,h64+e]; scale+softmax ----
__global__ __launch_bounds__(256) void gsmall_k(
    const float* __restrict__ T2f, const float* __restrict__ Wq,
    const float* __restrict__ qinv, const float* __restrict__ kinv,
    const float* __restrict__ resc, float* __restrict__ att)
{
    __shared__ float t2l[64][64], wql[64][64];
    int t = threadIdx.x, h = blockIdx.x, b = blockIdx.y;
    int e = t & 63, g4 = t >> 6;
    float acc[16];
#pragma unroll
    for (int r = 0; r < 16; r++) acc[r] = 0.f;
    for (int c0 = 0; c0 < 512; c0 += 64) {
        __syncthreads();
        for (int i = t; i < 4096; i += 256) {
            int cc = i >> 6, j = i & 63;
            t2l[cc][j] = T2f[(size_t)(b * 512 + c0 + cc) * 512 + h * 64 + j];
            wql[cc][j] = Wq[(size_t)(c0 + cc) * 512 + h * 64 + j];
        }
        __syncthreads();
        for (int cc = 0; cc < 64; cc++) {
            float qv = wql[cc][e];
#pragma unroll
            for (int r = 0; r < 16; r++) acc[r] += t2l[cc][g4 * 16 + r] * qv;
        }
    }
    float qn = qinv[b * 512 + h * 64 + e];
    float rs = resc[h];
    float* ap = att + (size_t)(b * 8 + h) * 4096;
    for (int r = 0; r < 16; r++) {
        int d = g4 * 16 + r;
        float v = acc[r] * kinv[b * 512 + h * 64 + d] * qn * rs;
        float m = v;
        for (int off = 32; off; off >>= 1) m = fmaxf(m, __shfl_xor(m, off));
        float ev = expf(v - m);
        float s = ev;
        for (int off = 32; off; off >>= 1) s += __shfl_xor(s, off);
        ap[d * 64 + e] = ev / s;
    }
}

// ---------------- M[b] fold: Mnt[b][o][h64+e] = sum_d att[b,h,d,e]*projW[h64+d][o] ---
__global__ __launch_bounds__(256) void mbuild_k(const float* __restrict__ attn,
                                                const float* __restrict__ projW,
                                                u16* Mnt)
{
    __shared__ float at[64][64];
    __shared__ float pw[64][64];
    int t = threadIdx.x;
    int h = blockIdx.x, b = blockIdx.y;
    int e = t & 63, g4 = t >> 6;
    const float* ap = attn + (size_t)(b * NHEAD + h) * 4096;
    for (int i = t; i < 4096; i += 256) at[i >> 6][i & 63] = ap[i];
    for (int ot = 0; ot < 8; ot++) {
        __syncthreads();
        for (int i = t; i < 4096; i += 256)
            pw[i >> 6][i & 63] = projW[(size_t)(h * 64 + (i >> 6)) * CH + ot * 64 + (i & 63)];
        __syncthreads();
        float acc[16];
#pragma unroll
        for (int r = 0; r < 16; r++) acc[r] = 0.f;
        for (int dd = 0; dd < 64; dd++) {
            float av = at[dd][e];
#pragma unroll
            for (int r = 0; r < 16; r++) acc[r] += av * pw[dd][g4 * 16 + r];
        }
#pragma unroll
        for (int r = 0; r < 16; r++)
            Mnt[(size_t)b * (CH * CH) + (size_t)(ot * 64 + g4 * 16 + r) * CH + h * 64 + e]
                = f2bf(acc[r]);
        __syncthreads();
    }
}

// ---------------- NHWC depthwise conv on compact [b,n,512] bf16 ----------------
// outAdd!=null: fp32 accumulate into outAdd (stride 512). else bf16 store,
// RESID adds in[] at center.
template<int KS, bool GELU_F, bool RESID>
__global__ __launch_bounds__(256) void dwconv_k(const u16* __restrict__ in,
                                                const float* __restrict__ w,
                                                u16* __restrict__ outB,
                                                float* __restrict__ outAdd)
{
    int idx = blockIdx.x * 256 + threadIdx.x;
    int cc = idx & 511;
    int pix = idx >> 9;
    int x = pix & 127, y = (pix >> 7) & 127, bb = pix >> 14;
    const int pad = KS / 2;
    float acc = 0.f;
    const float* wp = w + cc * KS * KS;
#pragma unroll
    for (int ky = 0; ky < KS; ky++) {
        int iy = y + ky - pad;
        if (iy < 0 || iy > 127) continue;
#pragma unroll
        for (int kx = 0; kx < KS; kx++) {
            int ix = x + kx - pad;
            if (ix < 0 || ix > 127) continue;
            size_t pin = (size_t)(bb * NPIX + iy * 128 + ix);
            acc += wp[ky * KS + kx] * bf2f(in[pin * CH + cc]);
        }
    }
    if (GELU_F) acc = 0.5f * acc * (1.f + erff(acc * 0.70710678118654752f));
    size_t pc = (size_t)pix * CH + cc;
    if (outAdd) {
        outAdd[pc] += acc;
    } else {
        float res = acc;
        if (RESID) res += bf2f(in[pc]);
        outB[pc] = f2bf(res);
    }
}

// ---------------- LayerNorm over c=512 per pixel, bf16 out ----------------
__global__ void ln_k(const float* __restrict__ xf, const float* __restrict__ g,
                     const float* __restrict__ bb, u16* __restrict__ xn)
{
    int t = threadIdx.x, lane = t & 63, wv = t >> 6;
    size_t pix = (size_t)blockIdx.x * 4 + wv;
    const float* row = xf + pix * CH;
    float4 a = *(const float4*)&row[lane * 8];
    float4 c = *(const float4*)&row[lane * 8 + 4];
    float s = a.x + a.y + a.z + a.w + c.x + c.y + c.z + c.w;
    float sq = a.x * a.x + a.y * a.y + a.z * a.z + a.w * a.w
             + c.x * c.x + c.y * c.y + c.z * c.z + c.w * c.w;
    for (int off = 32; off; off >>= 1) {
        s  += __shfl_xor(s, off);
        sq += __shfl_xor(sq, off);
    }
    float mu = s * (1.f / 512.f);
    float var = fmaxf(sq * (1.f / 512.f) - mu * mu, 0.f);
    float inv = rsqrtf(var + 1e-5f);
    float vals[8] = {a.x, a.y, a.z, a.w, c.x, c.y, c.z, c.w};
    unsigned o[4];
#pragma unroll
    for (int j = 0; j < 4; j++) {
        int cix = lane * 8 + j * 2;
        float v0 = (vals[j * 2] - mu) * inv * g[cix] + bb[cix];
        float v1 = (vals[j * 2 + 1] - mu) * inv * g[cix + 1] + bb[cix + 1];
        o[j] = (unsigned)f2bf(v0) | ((unsigned)f2bf(v1) << 16);
    }
    *(uint4*)&xn[pix * CH + lane * 8] = make_uint4(o[0], o[1], o[2], o[3]);
}

// =====================================================================
extern "C" void kernel_launch(void* const* d_in, const int* in_sizes, int n_in,
                              void* d_out, int out_size, void* d_ws, size_t ws_size,
                              hipStream_t stream)
{
    (void)in_sizes; (void)n_in; (void)out_size; (void)ws_size;
    const float* x_in  = (const float*)d_in[0];
    const float* Wq    = (const float*)d_in[1];
    const float* Wk    = (const float*)d_in[2];
    const float* Wv    = (const float*)d_in[3];
    const float* resc  = (const float*)d_in[4];
    const float* projW = (const float*)d_in[5];
    const float* projB = (const float*)d_in[6];
    const float* posw1 = (const float*)d_in[7];
    const float* posw2 = (const float*)d_in[8];
    const float* lng   = (const float*)d_in[9];
    const float* lnb   = (const float*)d_in[10];
    const float* w1    = (const float*)d_in[11];
    const float* dw1   = (const float*)d_in[12];
    const float* dw3   = (const float*)d_in[13];
    const float* dw5   = (const float*)d_in[14];
    const float* dw7   = (const float*)d_in[15];
    const float* w2    = (const float*)d_in[16];
    float* out = (float*)d_out;
    char* ws = (char*)d_ws;

    // ---- d_ws layout (~113 MB) ----
    float* XF  = (float*)(ws + 0);               // 64 MB fp32 state [b,n,c]
    u16*   XBb = (u16*)  (ws + 67108864ull);     // 32 MB bf16 x / xn [b,n,c]
    u16*   WQt = (u16*)  (ws + 100663296ull);    // 1 MB [2][512][512]
    u16*   WKt = (u16*)  (ws + 101711872ull);    // 1 MB
    u16*   WVt = (u16*)  (ws + 102760448ull);    // 1 MB
    u16*   W1b = (u16*)  (ws + 103809024ull);    // 4 MB [2][2048][512]
    u16*   W2b = (u16*)  (ws + 108003328ull);    // 4 MB [2][512][2048]
    u16*   Mnt = (u16*)  (ws + 112197632ull);    // 1 MB [2][512][512]
    u16*   Sbf = (u16*)  (ws + 113246208ull);    // 1 MB [2][512][512]
    float* T1f = (float*)(ws + 114294784ull);    // 2 MB [2][512][512]
    float* T2f = (float*)(ws + 116391936ull);    // 2 MB
    float* QNI = (float*)(ws + 118489088ull);    // 4 KB [2][512]
    float* KNI = (float*)(ws + 118493184ull);    // 4 KB
    float* ATT = (float*)(ws + 118497280ull);    // 256 KB [2][8][64][64]

    // ---- d_out used as scratch until the final transpose ----
    u16*   R2 = (u16*)d_out;                     // 32 MB: XT / posT1 / Og
    u16*   R3 = (u16*)d_out + 16777216;          // 32 MB: Vb / Yg
    float* Sp = (float*)((char*)d_out + 33554432ull); // 16 MB split-K partials (pre-V)

    const int BIG = 1 << 30;
    dim3 tb(32, 8);

    // prep: x [b,c,n] -> XF/XBb [b,n,c]; weight transposes / converts
    transpose_k<<<dim3(512, 16, 2), tb, 0, stream>>>(x_in, XF, XBb, 512, 16384, 8388608, 8388608);
    transpose_k<<<dim3(16, 16, 2), tb, 0, stream>>>(Wq, nullptr, WQt, 512, 512, 262144, 262144);
    transpose_k<<<dim3(16, 16, 2), tb, 0, stream>>>(Wk, nullptr, WKt, 512, 512, 262144, 262144);
    transpose_k<<<dim3(16, 16, 2), tb, 0, stream>>>(Wv, nullptr, WVt, 512, 512, 262144, 262144);
    cvt_bf16_k<<<2048, 256, 0, stream>>>(w1, W1b);
    cvt_bf16_k<<<2048, 256, 0, stream>>>(w2, W2b);

    for (int l = 0; l < 2; l++) {
        // XT (bf16 [b][c][n]) into R2
        if (l == 0)
            cvt_bf16_k<<<16384, 256, 0, stream>>>(x_in, R2);
        else
            transpose16_k<<<dim3(16, 512, 2), tb, 0, stream>>>(XBb, R2, 16384, 512, 8388608, 8388608);
        // S = X^T X per batch: split-K (8 x 2048) partials into Sp
        gemm_nt_k<<<dim3(4, 8, 8), 256, 0, stream>>>(R2, R2, 16384, 16384, 512,
            512, 8388608, 2048, nullptr, nullptr, Sp, nullptr);
        sreduce_k<<<2048, 256, 0, stream>>>(Sp, Sbf);
        // T1 = S*Wq, T2 = S*Wk (fp32 out)
        gemm_nt_k<<<dim3(4, 8), 256, 0, stream>>>(Sbf, WQt + l * 262144, 512, 512, 512,
            BIG, 0, 0, nullptr, nullptr, T1f, nullptr);
        gemm_nt_k<<<dim3(4, 8), 256, 0, stream>>>(Sbf, WKt + l * 262144, 512, 512, 512,
            BIG, 0, 0, nullptr, nullptr, T2f, nullptr);
        nrm_k<<<8, 256, 0, stream>>>(Wq + l * 262144, T1f, QNI);
        nrm_k<<<8, 256, 0, stream>>>(Wk + l * 262144, T2f, KNI);
        gsmall_k<<<dim3(8, 2), 256, 0, stream>>>(T2f, Wq + l * 262144, QNI, KNI,
            resc + l * 8, ATT);
        mbuild_k<<<dim3(8, 2), 256, 0, stream>>>(ATT, projW + l * 262144, Mnt);
        // V = x @ Wv  (bf16, into R3; Sp dead by now)
        gemm_nt_k<<<dim3(4, 256), 256, 0, stream>>>(XBb, WVt + l * 262144, 512, 512, 512,
            BIG, 0, 0, nullptr, nullptr, nullptr, R3);
        // x += V @ M^T + proj_b  (fused attn-apply + proj + residual)
        gemm_nt_k<<<dim3(4, 256), 256, 0, stream>>>(R3, Mnt, 512, 512, 512,
            16384, 262144, 0, projB + l * 512, XF, XF, nullptr);
        // positional branch: dwconv3(gelu) then dwconv3 accumulated into XF
        dwconv_k<3, true, false><<<65536, 256, 0, stream>>>(R3, posw1 + l * 4608, R2, nullptr);
        dwconv_k<3, false, false><<<65536, 256, 0, stream>>>(R2, posw2 + l * 4608, nullptr, XF);
        // PreNorm
        ln_k<<<8192, 256, 0, stream>>>(XF, lng + l * 512, lnb + l * 512, XBb);
        // MS-FFN, group-streamed: up -> dwconv(+y) -> down accumulate into XF
        for (int g = 0; g < 4; g++) {
            gemm_nt_k<<<dim3(4, 256), 256, 0, stream>>>(XBb,
                W1b + l * 1048576 + g * 262144, 512, 512, 512,
                BIG, 0, 0, nullptr, nullptr, nullptr, R3);
            if (g == 0)
                dwconv_k<1, false, true><<<65536, 256, 0, stream>>>(R3, dw1 + l * 512, R2, nullptr);
            else if (g == 1)
                dwconv_k<3, false, true><<<65536, 256, 0, stream>>>(R3, dw3 + l * 4608, R2, nullptr);
            else if (g == 2)
                dwconv_k<5, false, true><<<65536, 256, 0, stream>>>(R3, dw5 + l * 12800, R2, nullptr);
            else
                dwconv_k<7, false, true><<<65536, 256, 0, stream>>>(R3, dw7 + l * 25088, R2, nullptr);
            gemm_nt_k<<<dim3(4, 256), 256, 0, stream>>>(R2,
                W2b + l * 1048576 + g * 512, 512, 2048, 512,
                BIG, 0, 0, nullptr, XF, XF, (g == 3) ? XBb : nullptr);
        }
    }
    // final: XF [b,n,c] -> out [b,c,n]
    transpose_k<<<dim3(16, 512, 2), tb, 0, stream>>>(XF, out, nullptr, 16384, 512, 8388608, 8388608);
}

// Round 3
// 2673.116 us; speedup vs baseline: 2.7110x; 2.7110x over previous
//
#include <hip/hip_runtime.h>
#include <math.h>

typedef unsigned short u16;
typedef short bf16x8 __attribute__((ext_vector_type(8)));
typedef float f32x4 __attribute__((ext_vector_type(4)));
typedef float f32x2 __attribute__((ext_vector_type(2)));

__device__ __forceinline__ float bf2f(u16 h) {
    union { unsigned u; float f; } v; v.u = ((unsigned)h) << 16; return v.f;
}
__device__ __forceinline__ u16 f2bf(float f) {
    union { float f; unsigned u; } v; v.f = f;
    unsigned r = v.u + 0x7fffu + ((v.u >> 16) & 1u);
    return (u16)(r >> 16);
}
__device__ __forceinline__ f32x2 up2(unsigned u) {
    union { unsigned v; float f; } lo, hi;
    lo.v = u << 16; hi.v = u & 0xffff0000u;
    f32x2 r; r.x = lo.f; r.y = hi.f; return r;
}

#define CH    512
#define NPIX  16384
#define PTOT  32768
#define NHEAD 8

// ---------------- fp32 transpose [R][Cc] -> [Cc][R] per z slab ----------------
__global__ void transpose_k(const float* __restrict__ in, float* outF, u16* outB,
                            int R, int Cc, size_t ibs, size_t obs)
{
    __shared__ float tile[32][33];
    int z = blockIdx.z;
    const float* ip = in + (size_t)z * ibs;
    int c0 = blockIdx.x * 32, r0 = blockIdx.y * 32;
    int tx = threadIdx.x, ty = threadIdx.y;
#pragma unroll
    for (int j = 0; j < 4; j++)
        tile[ty + j * 8][tx] = ip[(size_t)(r0 + ty + j * 8) * Cc + c0 + tx];
    __syncthreads();
#pragma unroll
    for (int j = 0; j < 4; j++) {
        int orow = c0 + ty + j * 8, ocol = r0 + tx;
        float v = tile[tx][ty + j * 8];
        size_t o = (size_t)z * obs + (size_t)orow * R + ocol;
        if (outF) outF[o] = v;
        if (outB) outB[o] = f2bf(v);
    }
}

// ---------------- bf16 transpose [R][Cc] -> [Cc][R] per z slab ----------------
__global__ void transpose16_k(const u16* __restrict__ in, u16* __restrict__ out,
                              int R, int Cc, size_t ibs, size_t obs)
{
    __shared__ u16 tile[32][34];
    int z = blockIdx.z;
    const u16* ip = in + (size_t)z * ibs;
    int c0 = blockIdx.x * 32, r0 = blockIdx.y * 32;
    int tx = threadIdx.x, ty = threadIdx.y;
#pragma unroll
    for (int j = 0; j < 4; j++)
        tile[ty + j * 8][tx] = ip[(size_t)(r0 + ty + j * 8) * Cc + c0 + tx];
    __syncthreads();
#pragma unroll
    for (int j = 0; j < 4; j++)
        out[(size_t)z * obs + (size_t)(c0 + ty + j * 8) * R + r0 + tx] = tile[tx][ty + j * 8];
}

// ---------------- fp32 -> bf16 convert (4 elems/thread) ----------------
__global__ void cvt_bf16_k(const float* __restrict__ in, u16* __restrict__ out)
{
    size_t i = ((size_t)blockIdx.x * 256 + threadIdx.x) * 4;
    float4 v = *(const float4*)&in[i];
    uint2 st;
    st.x = (unsigned)f2bf(v.x) | ((unsigned)f2bf(v.y) << 16);
    st.y = (unsigned)f2bf(v.z) | ((unsigned)f2bf(v.w) << 16);
    *(uint2*)&out[i] = st;
}

// ---------------- bf16 NT GEMM: out[i,o] = sum_k A[i,k]*B[o,k] ----------------
__global__ __launch_bounds__(256) void gemm_nt_k(
    const u16* __restrict__ A, const u16* __restrict__ Bw,
    int K, int ldb, int Nn, int rowsPerBatch, int bStride, int kChunk,
    const float* __restrict__ bias, const float* resid,
    float* outF, u16* outB)
{
    __shared__ u16 As[128 * 32];
    __shared__ u16 Bs[128 * 32];
    int tid = threadIdx.x;
    int rowBase = blockIdx.y * 128, colBase = blockIdx.x * 128;
    const u16* Bp = Bw + (size_t)(rowBase / rowsPerBatch) * bStride;

    int kb = 0, ke = K;
    float* outFp = outF;
    if (kChunk) {
        kb = blockIdx.z * kChunk; ke = kb + kChunk;
        outFp = outF + (size_t)blockIdx.z * (size_t)gridDim.y * 128 * Nn;
    }

    f32x4 acc[4][4] = {};
    int lane = tid & 63, wave = tid >> 6;
    int wr = wave >> 1, wc = wave & 1;
    int lm = lane & 15, lk = lane >> 4;

    for (int k0 = kb; k0 < ke; k0 += 32) {
        __syncthreads();
#pragma unroll
        for (int j = 0; j < 2; j++) {
            int ch = j * 256 + tid;
            int row = ch >> 2, kc = (ch & 3) * 8;
            *(uint4*)&As[row * 32 + kc] =
                *(const uint4*)&A[(size_t)(rowBase + row) * K + k0 + kc];
            *(uint4*)&Bs[row * 32 + kc] =
                *(const uint4*)&Bp[(size_t)(colBase + row) * ldb + k0 + kc];
        }
        __syncthreads();
        bf16x8 af[4], bfr[4];
#pragma unroll
        for (int mt = 0; mt < 4; mt++)
            af[mt] = *(const bf16x8*)&As[(wr * 64 + mt * 16 + lm) * 32 + lk * 8];
#pragma unroll
        for (int nt = 0; nt < 4; nt++)
            bfr[nt] = *(const bf16x8*)&Bs[(wc * 64 + nt * 16 + lm) * 32 + lk * 8];
#pragma unroll
        for (int mt = 0; mt < 4; mt++)
#pragma unroll
            for (int nt = 0; nt < 4; nt++)
                acc[mt][nt] = __builtin_amdgcn_mfma_f32_16x16x32_bf16(
                    af[mt], bfr[nt], acc[mt][nt], 0, 0, 0);
    }

#pragma unroll
    for (int mt = 0; mt < 4; mt++)
#pragma unroll
        for (int nt = 0; nt < 4; nt++) {
            int col = colBase + wc * 64 + nt * 16 + lm;
            float bv = bias ? bias[col] : 0.f;
#pragma unroll
            for (int r = 0; r < 4; r++) {
                int row = rowBase + wr * 64 + mt * 16 + lk * 4 + r;
                size_t o = (size_t)row * Nn + col;
                float v = acc[mt][nt][r] + bv;
                if (resid) v += resid[o];
                if (outFp) outFp[o] = v;
                if (outB) outB[o] = f2bf(v);
            }
        }
}

// ---------------- reduce 8 split-K partials -> bf16 ----------------
__global__ void sreduce_k(const float* __restrict__ Sp, u16* __restrict__ Sbf)
{
    int i = blockIdx.x * 256 + threadIdx.x;
    float s = 0.f;
#pragma unroll
    for (int z = 0; z < 8; z++) s += Sp[(size_t)z * 524288 + i];
    Sbf[i] = f2bf(s);
}

// ---------------- inv l2 norms ----------------
__global__ void nrm_k(const float* __restrict__ w, const float* __restrict__ Tf,
                      float* __restrict__ inv)
{
    int idx = blockIdx.x * 256 + threadIdx.x;   // 0..2047
    int e = idx & 511, b = idx >> 9;
    float s = 0.f;
    for (int c = 0; c < 512; c++)
        s += w[c * 512 + e] * Tf[(size_t)(b * 512 + c) * 512 + e];
    s = fmaxf(s, 0.f);
    inv[b * 512 + e] = 1.f / fmaxf(sqrtf(s), 1e-12f);
}

// ---------------- G[b,h,d,e]=sum_c T2[b,c,h64+d]*Wq[c,h64+e]; scale+softmax ----
__global__ __launch_bounds__(256) void gsmall_k(
    const float* __restrict__ T2f, const float* __restrict__ Wq,
    const float* __restrict__ qinv, const float* __restrict__ kinv,
    const float* __restrict__ resc, float* __restrict__ att)
{
    __shared__ float t2l[64][64], wql[64][64];
    int t = threadIdx.x, h = blockIdx.x, b = blockIdx.y;
    int e = t & 63, g4 = t >> 6;
    float acc[16];
#pragma unroll
    for (int r = 0; r < 16; r++) acc[r] = 0.f;
    for (int c0 = 0; c0 < 512; c0 += 64) {
        __syncthreads();
        for (int i = t; i < 4096; i += 256) {
            int cc = i >> 6, j = i & 63;
            t2l[cc][j] = T2f[(size_t)(b * 512 + c0 + cc) * 512 + h * 64 + j];
            wql[cc][j] = Wq[(size_t)(c0 + cc) * 512 + h * 64 + j];
        }
        __syncthreads();
        for (int cc = 0; cc < 64; cc++) {
            float qv = wql[cc][e];
#pragma unroll
            for (int r = 0; r < 16; r++) acc[r] += t2l[cc][g4 * 16 + r] * qv;
        }
    }
    float qn = qinv[b * 512 + h * 64 + e];
    float rs = resc[h];
    float* ap = att + (size_t)(b * 8 + h) * 4096;
    for (int r = 0; r < 16; r++) {
        int d = g4 * 16 + r;
        float v = acc[r] * kinv[b * 512 + h * 64 + d] * qn * rs;
        float m = v;
        for (int off = 32; off; off >>= 1) m = fmaxf(m, __shfl_xor(m, off));
        float ev = expf(v - m);
        float s = ev;
        for (int off = 32; off; off >>= 1) s += __shfl_xor(s, off);
        ap[d * 64 + e] = ev / s;
    }
}

// ---------------- M[b] fold ----------------
__global__ __launch_bounds__(256) void mbuild_k(const float* __restrict__ attn,
                                                const float* __restrict__ projW,
                                                u16* Mnt)
{
    __shared__ float at[64][64];
    __shared__ float pw[64][64];
    int t = threadIdx.x;
    int h = blockIdx.x, b = blockIdx.y;
    int e = t & 63, g4 = t >> 6;
    const float* ap = attn + (size_t)(b * NHEAD + h) * 4096;
    for (int i = t; i < 4096; i += 256) at[i >> 6][i & 63] = ap[i];
    for (int ot = 0; ot < 8; ot++) {
        __syncthreads();
        for (int i = t; i < 4096; i += 256)
            pw[i >> 6][i & 63] = projW[(size_t)(h * 64 + (i >> 6)) * CH + ot * 64 + (i & 63)];
        __syncthreads();
        float acc[16];
#pragma unroll
        for (int r = 0; r < 16; r++) acc[r] = 0.f;
        for (int dd = 0; dd < 64; dd++) {
            float av = at[dd][e];
#pragma unroll
            for (int r = 0; r < 16; r++) acc[r] += av * pw[dd][g4 * 16 + r];
        }
#pragma unroll
        for (int r = 0; r < 16; r++)
            Mnt[(size_t)b * (CH * CH) + (size_t)(ot * 64 + g4 * 16 + r) * CH + h * 64 + e]
                = f2bf(acc[r]);
        __syncthreads();
    }
}

// ============ register-sliding-window NHWC depthwise conv ============
// layout [b, y(128), x(128), c(512)] bf16.  thread = (channel-pair, x);
// strip of YS rows per block.  Window + weights live in registers as f32x2
// (2 channels/lane -> v_pk_fma_f32).  Loads: KS u32 per y-step.
template<int KS, int YS, bool GELU_F, bool RESID, bool ACC>
__global__ __launch_bounds__(256, 1) void dwreg_k(
    const u16* __restrict__ in, const float* __restrict__ w,
    u16* __restrict__ outB, float* __restrict__ outAdd)
{
    constexpr int PAD = KS / 2;
    const int cp = threadIdx.x;          // channel pair 0..255
    const int x  = blockIdx.x;           // 0..127
    const int y0 = blockIdx.y * YS;
    const int b  = blockIdx.z;

    // per-thread weights (2 channels)
    f32x2 wv[KS * KS];
    {
        const float* w0 = w + (cp * 2) * (KS * KS);
#pragma unroll
        for (int t = 0; t < KS * KS; t++) {
            f32x2 v; v.x = w0[t]; v.y = w0[KS * KS + t];
            wv[t] = v;
        }
    }

    f32x2 win[KS][KS];

    auto loadrow = [&](int t, int slot) {
        int yy = y0 - PAD + t;
        bool rv = ((unsigned)yy < 128u);
#pragma unroll
        for (int kx = 0; kx < KS; kx++) {
            int xx = x + kx - PAD;
            f32x2 v; v.x = 0.f; v.y = 0.f;
            if (rv && ((unsigned)xx < 128u)) {
                long pix = (long)b * NPIX + (long)yy * 128 + xx;
                unsigned u = *(const unsigned*)&in[pix * 512 + cp * 2];
                v = up2(u);
            }
            win[slot][kx] = v;
        }
    };

    // prologue: rows t = 0..KS-2 into slots t
#pragma unroll
    for (int t = 0; t < KS - 1; t++) loadrow(t, t);

    for (int i0 = 0; i0 < YS; i0 += KS) {
#pragma unroll
        for (int j = 0; j < KS; j++) {
            int i = i0 + j;
            if (i >= YS) break;
            // bring in row t = i+KS-1 at slot (j+KS-1)%KS
            loadrow(i + KS - 1, (j + KS - 1) % KS);

            f32x2 a[4] = {};
#pragma unroll
            for (int ky = 0; ky < KS; ky++)
#pragma unroll
                for (int kx = 0; kx < KS; kx++)
                    a[ky & 3] += win[(j + ky) % KS][kx] * wv[ky * KS + kx];
            f32x2 r = (a[0] + a[1]) + (a[2] + a[3]);

            if (GELU_F) {
                r.x = 0.5f * r.x * (1.f + erff(r.x * 0.70710678118654752f));
                r.y = 0.5f * r.y * (1.f + erff(r.y * 0.70710678118654752f));
            }
            if (RESID) r += win[(j + PAD) % KS][PAD];

            long opix = (long)b * NPIX + (long)(y0 + i) * 128 + x;
            if (ACC) {
                f32x2* p = (f32x2*)&outAdd[opix * 512 + cp * 2];
                *p = *p + r;
            } else {
                unsigned pk = (unsigned)f2bf(r.x) | ((unsigned)f2bf(r.y) << 16);
                *(unsigned*)&outB[opix * 512 + cp * 2] = pk;
            }
        }
    }
}

// ---------------- LayerNorm over c=512 per pixel, bf16 out ----------------
__global__ void ln_k(const float* __restrict__ xf, const float* __restrict__ g,
                     const float* __restrict__ bb, u16* __restrict__ xn)
{
    int t = threadIdx.x, lane = t & 63, wv = t >> 6;
    size_t pix = (size_t)blockIdx.x * 4 + wv;
    const float* row = xf + pix * CH;
    float4 a = *(const float4*)&row[lane * 8];
    float4 c = *(const float4*)&row[lane * 8 + 4];
    float s = a.x + a.y + a.z + a.w + c.x + c.y + c.z + c.w;
    float sq = a.x * a.x + a.y * a.y + a.z * a.z + a.w * a.w
             + c.x * c.x + c.y * c.y + c.z * c.z + c.w * c.w;
    for (int off = 32; off; off >>= 1) {
        s  += __shfl_xor(s, off);
        sq += __shfl_xor(sq, off);
    }
    float mu = s * (1.f / 512.f);
    float var = fmaxf(sq * (1.f / 512.f) - mu * mu, 0.f);
    float inv = rsqrtf(var + 1e-5f);
    float vals[8] = {a.x, a.y, a.z, a.w, c.x, c.y, c.z, c.w};
    unsigned o[4];
#pragma unroll
    for (int j = 0; j < 4; j++) {
        int cix = lane * 8 + j * 2;
        float v0 = (vals[j * 2] - mu) * inv * g[cix] + bb[cix];
        float v1 = (vals[j * 2 + 1] - mu) * inv * g[cix + 1] + bb[cix + 1];
        o[j] = (unsigned)f2bf(v0) | ((unsigned)f2bf(v1) << 16);
    }
    *(uint4*)&xn[pix * CH + lane * 8] = make_uint4(o[0], o[1], o[2], o[3]);
}

// =====================================================================
extern "C" void kernel_launch(void* const* d_in, const int* in_sizes, int n_in,
                              void* d_out, int out_size, void* d_ws, size_t ws_size,
                              hipStream_t stream)
{
    (void)in_sizes; (void)n_in; (void)out_size; (void)ws_size;
    const float* x_in  = (const float*)d_in[0];
    const float* Wq    = (const float*)d_in[1];
    const float* Wk    = (const float*)d_in[2];
    const float* Wv    = (const float*)d_in[3];
    const float* resc  = (const float*)d_in[4];
    const float* projW = (const float*)d_in[5];
    const float* projB = (const float*)d_in[6];
    const float* posw1 = (const float*)d_in[7];
    const float* posw2 = (const float*)d_in[8];
    const float* lng   = (const float*)d_in[9];
    const float* lnb   = (const float*)d_in[10];
    const float* w1    = (const float*)d_in[11];
    const float* dw1   = (const float*)d_in[12];
    const float* dw3   = (const float*)d_in[13];
    const float* dw5   = (const float*)d_in[14];
    const float* dw7   = (const float*)d_in[15];
    const float* w2    = (const float*)d_in[16];
    float* out = (float*)d_out;
    char* ws = (char*)d_ws;

    // ---- d_ws layout (~113 MB) ----
    float* XF  = (float*)(ws + 0);               // 64 MB fp32 state [b,n,c]
    u16*   XBb = (u16*)  (ws + 67108864ull);     // 32 MB bf16 x / xn [b,n,c]
    u16*   WQt = (u16*)  (ws + 100663296ull);    // 1 MB [2][512][512]
    u16*   WKt = (u16*)  (ws + 101711872ull);    // 1 MB
    u16*   WVt = (u16*)  (ws + 102760448ull);    // 1 MB
    u16*   W1b = (u16*)  (ws + 103809024ull);    // 4 MB [2][2048][512]
    u16*   W2b = (u16*)  (ws + 108003328ull);    // 4 MB [2][512][2048]
    u16*   Mnt = (u16*)  (ws + 112197632ull);    // 1 MB [2][512][512]
    u16*   Sbf = (u16*)  (ws + 113246208ull);    // 1 MB [2][512][512]
    float* T1f = (float*)(ws + 114294784ull);    // 2 MB [2][512][512]
    float* T2f = (float*)(ws + 116391936ull);    // 2 MB
    float* QNI = (float*)(ws + 118489088ull);    // 4 KB [2][512]
    float* KNI = (float*)(ws + 118493184ull);    // 4 KB
    float* ATT = (float*)(ws + 118497280ull);    // 256 KB [2][8][64][64]

    // ---- d_out used as scratch until the final transpose ----
    u16*   R2 = (u16*)d_out;                     // 32 MB: XT / posT1 / Og
    u16*   R3 = (u16*)d_out + 16777216;          // 32 MB: Vb / Yg
    float* Sp = (float*)((char*)d_out + 33554432ull); // 16 MB split-K partials (pre-V)

    const int BIG = 1 << 30;
    dim3 tb(32, 8);

    // prep
    transpose_k<<<dim3(512, 16, 2), tb, 0, stream>>>(x_in, XF, XBb, 512, 16384, 8388608, 8388608);
    transpose_k<<<dim3(16, 16, 2), tb, 0, stream>>>(Wq, nullptr, WQt, 512, 512, 262144, 262144);
    transpose_k<<<dim3(16, 16, 2), tb, 0, stream>>>(Wk, nullptr, WKt, 512, 512, 262144, 262144);
    transpose_k<<<dim3(16, 16, 2), tb, 0, stream>>>(Wv, nullptr, WVt, 512, 512, 262144, 262144);
    cvt_bf16_k<<<2048, 256, 0, stream>>>(w1, W1b);
    cvt_bf16_k<<<2048, 256, 0, stream>>>(w2, W2b);

    for (int l = 0; l < 2; l++) {
        // XT (bf16 [b][c][n]) into R2
        if (l == 0)
            cvt_bf16_k<<<16384, 256, 0, stream>>>(x_in, R2);
        else
            transpose16_k<<<dim3(16, 512, 2), tb, 0, stream>>>(XBb, R2, 16384, 512, 8388608, 8388608);
        // S = X^T X per batch: split-K partials
        gemm_nt_k<<<dim3(4, 8, 8), 256, 0, stream>>>(R2, R2, 16384, 16384, 512,
            512, 8388608, 2048, nullptr, nullptr, Sp, nullptr);
        sreduce_k<<<2048, 256, 0, stream>>>(Sp, Sbf);
        // T1 = S*Wq, T2 = S*Wk
        gemm_nt_k<<<dim3(4, 8), 256, 0, stream>>>(Sbf, WQt + l * 262144, 512, 512, 512,
            BIG, 0, 0, nullptr, nullptr, T1f, nullptr);
        gemm_nt_k<<<dim3(4, 8), 256, 0, stream>>>(Sbf, WKt + l * 262144, 512, 512, 512,
            BIG, 0, 0, nullptr, nullptr, T2f, nullptr);
        nrm_k<<<8, 256, 0, stream>>>(Wq + l * 262144, T1f, QNI);
        nrm_k<<<8, 256, 0, stream>>>(Wk + l * 262144, T2f, KNI);
        gsmall_k<<<dim3(8, 2), 256, 0, stream>>>(T2f, Wq + l * 262144, QNI, KNI,
            resc + l * 8, ATT);
        mbuild_k<<<dim3(8, 2), 256, 0, stream>>>(ATT, projW + l * 262144, Mnt);
        // V = x @ Wv
        gemm_nt_k<<<dim3(4, 256), 256, 0, stream>>>(XBb, WVt + l * 262144, 512, 512, 512,
            BIG, 0, 0, nullptr, nullptr, nullptr, R3);
        // x += V @ M^T + proj_b
        gemm_nt_k<<<dim3(4, 256), 256, 0, stream>>>(R3, Mnt, 512, 512, 512,
            16384, 262144, 0, projB + l * 512, XF, XF, nullptr);
        // positional branch: dwconv3 + gelu -> R2, then dwconv3 accumulated into XF
        dwreg_k<3, 16, true, false, false><<<dim3(128, 8, 2), 256, 0, stream>>>(
            R3, posw1 + l * 4608, R2, nullptr);
        dwreg_k<3, 16, false, false, true><<<dim3(128, 8, 2), 256, 0, stream>>>(
            R2, posw2 + l * 4608, nullptr, XF);
        // PreNorm
        ln_k<<<8192, 256, 0, stream>>>(XF, lng + l * 512, lnb + l * 512, XBb);
        // MS-FFN, group-streamed
        for (int g = 0; g < 4; g++) {
            gemm_nt_k<<<dim3(4, 256), 256, 0, stream>>>(XBb,
                W1b + l * 1048576 + g * 262144, 512, 512, 512,
                BIG, 0, 0, nullptr, nullptr, nullptr, R3);
            if (g == 0)
                dwreg_k<1, 16, false, true, false><<<dim3(128, 8, 2), 256, 0, stream>>>(
                    R3, dw1 + l * 512, R2, nullptr);
            else if (g == 1)
                dwreg_k<3, 16, false, true, false><<<dim3(128, 8, 2), 256, 0, stream>>>(
                    R3, dw3 + l * 4608, R2, nullptr);
            else if (g == 2)
                dwreg_k<5, 32, false, true, false><<<dim3(128, 4, 2), 256, 0, stream>>>(
                    R3, dw5 + l * 12800, R2, nullptr);
            else
                dwreg_k<7, 64, false, true, false><<<dim3(128, 2, 2), 256, 0, stream>>>(
                    R3, dw7 + l * 25088, R2, nullptr);
            gemm_nt_k<<<dim3(4, 256), 256, 0, stream>>>(R2,
                W2b + l * 1048576 + g * 512, 512, 2048, 512,
                BIG, 0, 0, nullptr, XF, XF, (g == 3) ? XBb : nullptr);
        }
    }
    // final: XF [b,n,c] -> out [b,c,n]
    transpose_k<<<dim3(16, 512, 2), tb, 0, stream>>>(XF, out, nullptr, 16384, 512, 8388608, 8388608);
}

// Round 4
// 2319.532 us; speedup vs baseline: 3.1243x; 1.1524x over previous
//
#include <hip/hip_runtime.h>
#include <math.h>

typedef unsigned short u16;
typedef short bf16x8 __attribute__((ext_vector_type(8)));
typedef float f32x4 __attribute__((ext_vector_type(4)));
typedef float f32x2 __attribute__((ext_vector_type(2)));

__device__ __forceinline__ float bf2f(u16 h) {
    union { unsigned u; float f; } v; v.u = ((unsigned)h) << 16; return v.f;
}
__device__ __forceinline__ u16 f2bf(float f) {
    union { float f; unsigned u; } v; v.f = f;
    unsigned r = v.u + 0x7fffu + ((v.u >> 16) & 1u);
    return (u16)(r >> 16);
}
__device__ __forceinline__ f32x2 up2(unsigned u) {
    union { unsigned v; float f; } lo, hi;
    lo.v = u << 16; hi.v = u & 0xffff0000u;
    f32x2 r; r.x = lo.f; r.y = hi.f; return r;
}
__device__ __forceinline__ f32x2 unpk(unsigned u) { return up2(u); }
__device__ __forceinline__ f32x4 unpk(uint2 u) {
    f32x2 a = up2(u.x), b = up2(u.y);
    f32x4 r; r.x = a.x; r.y = a.y; r.z = b.x; r.w = b.y; return r;
}
__device__ __forceinline__ unsigned pkbf(f32x2 v) {
    return (unsigned)f2bf(v.x) | ((unsigned)f2bf(v.y) << 16);
}
__device__ __forceinline__ uint2 pkbf(f32x4 v) {
    uint2 r;
    r.x = (unsigned)f2bf(v.x) | ((unsigned)f2bf(v.y) << 16);
    r.y = (unsigned)f2bf(v.z) | ((unsigned)f2bf(v.w) << 16);
    return r;
}
__device__ __forceinline__ float gl(float v) {
    return 0.5f * v * (1.f + erff(v * 0.70710678118654752f));
}

template<int N> struct VecT;
template<> struct VecT<2> { typedef f32x2 T; typedef unsigned U; };
template<> struct VecT<4> { typedef f32x4 T; typedef uint2 U; };

#define CH    512
#define NPIX  16384
#define PTOT  32768
#define NHEAD 8

// ---------------- fp32 transpose [R][Cc] -> [Cc][R] per z slab ----------------
__global__ void transpose_k(const float* __restrict__ in, float* outF, u16* outB,
                            int R, int Cc, size_t ibs, size_t obs)
{
    __shared__ float tile[32][33];
    int z = blockIdx.z;
    const float* ip = in + (size_t)z * ibs;
    int c0 = blockIdx.x * 32, r0 = blockIdx.y * 32;
    int tx = threadIdx.x, ty = threadIdx.y;
#pragma unroll
    for (int j = 0; j < 4; j++)
        tile[ty + j * 8][tx] = ip[(size_t)(r0 + ty + j * 8) * Cc + c0 + tx];
    __syncthreads();
#pragma unroll
    for (int j = 0; j < 4; j++) {
        int orow = c0 + ty + j * 8, ocol = r0 + tx;
        float v = tile[tx][ty + j * 8];
        size_t o = (size_t)z * obs + (size_t)orow * R + ocol;
        if (outF) outF[o] = v;
        if (outB) outB[o] = f2bf(v);
    }
}

// ---------------- bf16 transpose [R][Cc] -> [Cc][R] per z slab ----------------
__global__ void transpose16_k(const u16* __restrict__ in, u16* __restrict__ out,
                              int R, int Cc, size_t ibs, size_t obs)
{
    __shared__ u16 tile[32][34];
    int z = blockIdx.z;
    const u16* ip = in + (size_t)z * ibs;
    int c0 = blockIdx.x * 32, r0 = blockIdx.y * 32;
    int tx = threadIdx.x, ty = threadIdx.y;
#pragma unroll
    for (int j = 0; j < 4; j++)
        tile[ty + j * 8][tx] = ip[(size_t)(r0 + ty + j * 8) * Cc + c0 + tx];
    __syncthreads();
#pragma unroll
    for (int j = 0; j < 4; j++)
        out[(size_t)z * obs + (size_t)(c0 + ty + j * 8) * R + r0 + tx] = tile[tx][ty + j * 8];
}

// ---------------- fp32 -> bf16 convert (4 elems/thread) ----------------
__global__ void cvt_bf16_k(const float* __restrict__ in, u16* __restrict__ out)
{
    size_t i = ((size_t)blockIdx.x * 256 + threadIdx.x) * 4;
    float4 v = *(const float4*)&in[i];
    uint2 st;
    st.x = (unsigned)f2bf(v.x) | ((unsigned)f2bf(v.y) << 16);
    st.y = (unsigned)f2bf(v.z) | ((unsigned)f2bf(v.w) << 16);
    *(uint2*)&out[i] = st;
}

// ---------------- w2 convert with group-0 (1+dw1[c]) column prescale ----------
__global__ void cvtw2_k(const float* __restrict__ in, const float* __restrict__ dw1,
                        u16* __restrict__ out)
{
    size_t i = ((size_t)blockIdx.x * 256 + threadIdx.x) * 4;   // over 2*512*2048
    int c = (int)(i & 2047);
    int l = (int)(i >> 20);
    float4 v = *(const float4*)&in[i];
    if (c < 512) {
        v.x *= 1.f + dw1[l * 512 + c];
        v.y *= 1.f + dw1[l * 512 + c + 1];
        v.z *= 1.f + dw1[l * 512 + c + 2];
        v.w *= 1.f + dw1[l * 512 + c + 3];
    }
    uint2 st;
    st.x = (unsigned)f2bf(v.x) | ((unsigned)f2bf(v.y) << 16);
    st.y = (unsigned)f2bf(v.z) | ((unsigned)f2bf(v.w) << 16);
    *(uint2*)&out[i] = st;
}

// ---------------- bf16 NT GEMM: out[i,o] = sum_k A[i,k]*B[o,k] ----------------
__global__ __launch_bounds__(256) void gemm_nt_k(
    const u16* __restrict__ A, const u16* __restrict__ Bw,
    int K, int ldb, int Nn, int rowsPerBatch, int bStride, int kChunk,
    const float* __restrict__ bias, const float* resid,
    float* outF, u16* outB)
{
    __shared__ u16 As[128 * 32];
    __shared__ u16 Bs[128 * 32];
    int tid = threadIdx.x;
    int rowBase = blockIdx.y * 128, colBase = blockIdx.x * 128;
    const u16* Bp = Bw + (size_t)(rowBase / rowsPerBatch) * bStride;

    int kb = 0, ke = K;
    float* outFp = outF;
    if (kChunk) {
        kb = blockIdx.z * kChunk; ke = kb + kChunk;
        outFp = outF + (size_t)blockIdx.z * (size_t)gridDim.y * 128 * Nn;
    }

    f32x4 acc[4][4] = {};
    int lane = tid & 63, wave = tid >> 6;
    int wr = wave >> 1, wc = wave & 1;
    int lm = lane & 15, lk = lane >> 4;

    for (int k0 = kb; k0 < ke; k0 += 32) {
        __syncthreads();
#pragma unroll
        for (int j = 0; j < 2; j++) {
            int ch = j * 256 + tid;
            int row = ch >> 2, kc = (ch & 3) * 8;
            *(uint4*)&As[row * 32 + kc] =
                *(const uint4*)&A[(size_t)(rowBase + row) * K + k0 + kc];
            *(uint4*)&Bs[row * 32 + kc] =
                *(const uint4*)&Bp[(size_t)(colBase + row) * ldb + k0 + kc];
        }
        __syncthreads();
        bf16x8 af[4], bfr[4];
#pragma unroll
        for (int mt = 0; mt < 4; mt++)
            af[mt] = *(const bf16x8*)&As[(wr * 64 + mt * 16 + lm) * 32 + lk * 8];
#pragma unroll
        for (int nt = 0; nt < 4; nt++)
            bfr[nt] = *(const bf16x8*)&Bs[(wc * 64 + nt * 16 + lm) * 32 + lk * 8];
#pragma unroll
        for (int mt = 0; mt < 4; mt++)
#pragma unroll
            for (int nt = 0; nt < 4; nt++)
                acc[mt][nt] = __builtin_amdgcn_mfma_f32_16x16x32_bf16(
                    af[mt], bfr[nt], acc[mt][nt], 0, 0, 0);
    }

#pragma unroll
    for (int mt = 0; mt < 4; mt++)
#pragma unroll
        for (int nt = 0; nt < 4; nt++) {
            int col = colBase + wc * 64 + nt * 16 + lm;
            float bv = bias ? bias[col] : 0.f;
#pragma unroll
            for (int r = 0; r < 4; r++) {
                int row = rowBase + wr * 64 + mt * 16 + lk * 4 + r;
                size_t o = (size_t)row * Nn + col;
                float v = acc[mt][nt][r] + bv;
                if (resid) v += resid[o];
                if (outFp) outFp[o] = v;
                if (outB) outB[o] = f2bf(v);
            }
        }
}

// ---------------- reduce 8 split-K partials -> bf16 ----------------
__global__ void sreduce_k(const float* __restrict__ Sp, u16* __restrict__ Sbf)
{
    int i = blockIdx.x * 256 + threadIdx.x;
    float s = 0.f;
#pragma unroll
    for (int z = 0; z < 8; z++) s += Sp[(size_t)z * 524288 + i];
    Sbf[i] = f2bf(s);
}

// ---------------- inv l2 norms ----------------
__global__ void nrm_k(const float* __restrict__ w, const float* __restrict__ Tf,
                      float* __restrict__ inv)
{
    int idx = blockIdx.x * 256 + threadIdx.x;   // 0..2047
    int e = idx & 511, b = idx >> 9;
    float s = 0.f;
    for (int c = 0; c < 512; c++)
        s += w[c * 512 + e] * Tf[(size_t)(b * 512 + c) * 512 + e];
    s = fmaxf(s, 0.f);
    inv[b * 512 + e] = 1.f / fmaxf(sqrtf(s), 1e-12f);
}

// ---------------- G[b,h,d,e]=sum_c T2[b,c,h64+d]*Wq[c,h64+e]; scale+softmax ----
__global__ __launch_bounds__(256) void gsmall_k(
    const float* __restrict__ T2f, const float* __restrict__ Wq,
    const float* __restrict__ qinv, const float* __restrict__ kinv,
    const float* __restrict__ resc, float* __restrict__ att)
{
    __shared__ float t2l[64][64], wql[64][64];
    int t = threadIdx.x, h = blockIdx.x, b = blockIdx.y;
    int e = t & 63, g4 = t >> 6;
    float acc[16];
#pragma unroll
    for (int r = 0; r < 16; r++) acc[r] = 0.f;
    for (int c0 = 0; c0 < 512; c0 += 64) {
        __syncthreads();
        for (int i = t; i < 4096; i += 256) {
            int cc = i >> 6, j = i & 63;
            t2l[cc][j] = T2f[(size_t)(b * 512 + c0 + cc) * 512 + h * 64 + j];
            wql[cc][j] = Wq[(size_t)(c0 + cc) * 512 + h * 64 + j];
        }
        __syncthreads();
        for (int cc = 0; cc < 64; cc++) {
            float qv = wql[cc][e];
#pragma unroll
            for (int r = 0; r < 16; r++) acc[r] += t2l[cc][g4 * 16 + r] * qv;
        }
    }
    float qn = qinv[b * 512 + h * 64 + e];
    float rs = resc[h];
    float* ap = att + (size_t)(b * 8 + h) * 4096;
    for (int r = 0; r < 16; r++) {
        int d = g4 * 16 + r;
        float v = acc[r] * kinv[b * 512 + h * 64 + d] * qn * rs;
        float m = v;
        for (int off = 32; off; off >>= 1) m = fmaxf(m, __shfl_xor(m, off));
        float ev = expf(v - m);
        float s = ev;
        for (int off = 32; off; off >>= 1) s += __shfl_xor(s, off);
        ap[d * 64 + e] = ev / s;
    }
}

// ---------------- M[b] fold ----------------
__global__ __launch_bounds__(256) void mbuild_k(const float* __restrict__ attn,
                                                const float* __restrict__ projW,
                                                u16* Mnt)
{
    __shared__ float at[64][64];
    __shared__ float pw[64][64];
    int t = threadIdx.x;
    int h = blockIdx.x, b = blockIdx.y;
    int e = t & 63, g4 = t >> 6;
    const float* ap = attn + (size_t)(b * NHEAD + h) * 4096;
    for (int i = t; i < 4096; i += 256) at[i >> 6][i & 63] = ap[i];
    for (int ot = 0; ot < 8; ot++) {
        __syncthreads();
        for (int i = t; i < 4096; i += 256)
            pw[i >> 6][i & 63] = projW[(size_t)(h * 64 + (i >> 6)) * CH + ot * 64 + (i & 63)];
        __syncthreads();
        float acc[16];
#pragma unroll
        for (int r = 0; r < 16; r++) acc[r] = 0.f;
        for (int dd = 0; dd < 64; dd++) {
            float av = at[dd][e];
#pragma unroll
            for (int r = 0; r < 16; r++) acc[r] += av * pw[dd][g4 * 16 + r];
        }
#pragma unroll
        for (int r = 0; r < 16; r++)
            Mnt[(size_t)b * (CH * CH) + (size_t)(ot * 64 + g4 * 16 + r) * CH + h * 64 + e]
                = f2bf(acc[r]);
        __syncthreads();
    }
}

// ============ register-sliding-window NHWC depthwise conv (pipelined) ============
// layout [b, y(128), x(128), c(512)] bf16.
// CPT channels/thread (2 or 4). Raw packed row prefetched into tmp[] one full
// row ahead of its unpack+use; KS^2 packed-f32 FMAs per y-step.
template<int KS, int YS, int CPT, bool GELU_F, bool RESID, bool ACC>
__global__ __launch_bounds__(256, 1) void dwreg_k(
    const u16* __restrict__ in, const float* __restrict__ w,
    u16* __restrict__ outB, float* __restrict__ outAdd)
{
    constexpr int PAD = KS / 2;
    typedef typename VecT<CPT>::T fv;
    typedef typename VecT<CPT>::U uv;
    const int tid = threadIdx.x;
    const int cbase = (CPT == 4) ? ((tid & 127) * 4) : (tid * 2);
    const int x     = (CPT == 4) ? ((int)blockIdx.x * 2 + (tid >> 7)) : (int)blockIdx.x;
    const int y0 = blockIdx.y * YS;
    const int b  = blockIdx.z;
    const size_t base = (size_t)b * NPIX * 512 + cbase;

    // per-thread weights
    fv wv[KS * KS];
#pragma unroll
    for (int t = 0; t < KS * KS; t++) {
        fv vv;
        vv.x = w[(cbase + 0) * KS * KS + t];
        vv.y = w[(cbase + 1) * KS * KS + t];
        if constexpr (CPT == 4) {
            vv.z = w[(cbase + 2) * KS * KS + t];
            vv.w = w[(cbase + 3) * KS * KS + t];
        }
        wv[t] = vv;
    }

    fv win[KS][KS];
    uv tmp[KS];

    auto rowload = [&](int t) {            // raw load of input row (y0-PAD+t)
        int yy = y0 - PAD + t;
        bool rv = ((unsigned)yy < 128u);
#pragma unroll
        for (int kx = 0; kx < KS; kx++) {
            int xx = x + kx - PAD;
            uv u = {};
            if (rv && ((unsigned)xx < 128u))
                u = *(const uv*)&in[base + ((size_t)yy * 128 + xx) * 512];
            tmp[kx] = u;
        }
    };
    auto unpackrow = [&](int slot) {
#pragma unroll
        for (int kx = 0; kx < KS; kx++) win[slot][kx] = unpk(tmp[kx]);
    };

    // prologue: rows 0..KS-2 resident; row KS-1 in flight
#pragma unroll
    for (int t = 0; t < KS - 1; t++) { rowload(t); unpackrow(t); }
    rowload(KS - 1);

    for (int i0 = 0; i0 < YS; i0 += KS) {
#pragma unroll
        for (int j = 0; j < KS; j++) {
            int i = i0 + j;
            if (i >= YS) break;
            unpackrow((j + KS - 1) % KS);        // row i+KS-1 arrives
            if (i < YS - 1) rowload(i + KS);     // prefetch next row
            fv r = {};
#pragma unroll
            for (int ky = 0; ky < KS; ky++)
#pragma unroll
                for (int kx = 0; kx < KS; kx++)
                    r += win[(j + ky) % KS][kx] * wv[ky * KS + kx];
            if (GELU_F) {
                r.x = gl(r.x); r.y = gl(r.y);
                if constexpr (CPT == 4) { r.z = gl(r.z); r.w = gl(r.w); }
            }
            if (RESID) r += win[(j + PAD) % KS][PAD];
            size_t opos = base + ((size_t)(y0 + i) * 128 + x) * 512;
            if (ACC) {
                fv* p = (fv*)&outAdd[opos];
                *p = *p + r;
            } else {
                uv pk = pkbf(r);
                *(uv*)&outB[opos] = pk;
            }
        }
    }
}

// ---------------- LayerNorm over c=512 per pixel, bf16 out ----------------
__global__ void ln_k(const float* __restrict__ xf, const float* __restrict__ g,
                     const float* __restrict__ bb, u16* __restrict__ xn)
{
    int t = threadIdx.x, lane = t & 63, wv = t >> 6;
    size_t pix = (size_t)blockIdx.x * 4 + wv;
    const float* row = xf + pix * CH;
    float4 a = *(const float4*)&row[lane * 8];
    float4 c = *(const float4*)&row[lane * 8 + 4];
    float s = a.x + a.y + a.z + a.w + c.x + c.y + c.z + c.w;
    float sq = a.x * a.x + a.y * a.y + a.z * a.z + a.w * a.w
             + c.x * c.x + c.y * c.y + c.z * c.z + c.w * c.w;
    for (int off = 32; off; off >>= 1) {
        s  += __shfl_xor(s, off);
        sq += __shfl_xor(sq, off);
    }
    float mu = s * (1.f / 512.f);
    float var = fmaxf(sq * (1.f / 512.f) - mu * mu, 0.f);
    float inv = rsqrtf(var + 1e-5f);
    float vals[8] = {a.x, a.y, a.z, a.w, c.x, c.y, c.z, c.w};
    unsigned o[4];
#pragma unroll
    for (int j = 0; j < 4; j++) {
        int cix = lane * 8 + j * 2;
        float v0 = (vals[j * 2] - mu) * inv * g[cix] + bb[cix];
        float v1 = (vals[j * 2 + 1] - mu) * inv * g[cix + 1] + bb[cix + 1];
        o[j] = (unsigned)f2bf(v0) | ((unsigned)f2bf(v1) << 16);
    }
    *(uint4*)&xn[pix * CH + lane * 8] = make_uint4(o[0], o[1], o[2], o[3]);
}

// =====================================================================
extern "C" void kernel_launch(void* const* d_in, const int* in_sizes, int n_in,
                              void* d_out, int out_size, void* d_ws, size_t ws_size,
                              hipStream_t stream)
{
    (void)in_sizes; (void)n_in; (void)out_size; (void)ws_size;
    const float* x_in  = (const float*)d_in[0];
    const float* Wq    = (const float*)d_in[1];
    const float* Wk    = (const float*)d_in[2];
    const float* Wv    = (const float*)d_in[3];
    const float* resc  = (const float*)d_in[4];
    const float* projW = (const float*)d_in[5];
    const float* projB = (const float*)d_in[6];
    const float* posw1 = (const float*)d_in[7];
    const float* posw2 = (const float*)d_in[8];
    const float* lng   = (const float*)d_in[9];
    const float* lnb   = (const float*)d_in[10];
    const float* w1    = (const float*)d_in[11];
    const float* dw1   = (const float*)d_in[12];
    const float* dw3   = (const float*)d_in[13];
    const float* dw5   = (const float*)d_in[14];
    const float* dw7   = (const float*)d_in[15];
    const float* w2    = (const float*)d_in[16];
    float* out = (float*)d_out;
    char* ws = (char*)d_ws;

    // ---- d_ws layout (~113 MB) ----
    float* XF  = (float*)(ws + 0);               // 64 MB fp32 state [b,n,c]
    u16*   XBb = (u16*)  (ws + 67108864ull);     // 32 MB bf16 x / xn [b,n,c]
    u16*   WQt = (u16*)  (ws + 100663296ull);    // 1 MB [2][512][512]
    u16*   WKt = (u16*)  (ws + 101711872ull);    // 1 MB
    u16*   WVt = (u16*)  (ws + 102760448ull);    // 1 MB
    u16*   W1b = (u16*)  (ws + 103809024ull);    // 4 MB [2][2048][512]
    u16*   W2b = (u16*)  (ws + 108003328ull);    // 4 MB [2][512][2048]
    u16*   Mnt = (u16*)  (ws + 112197632ull);    // 1 MB [2][512][512]
    u16*   Sbf = (u16*)  (ws + 113246208ull);    // 1 MB [2][512][512]
    float* T1f = (float*)(ws + 114294784ull);    // 2 MB [2][512][512]
    float* T2f = (float*)(ws + 116391936ull);    // 2 MB
    float* QNI = (float*)(ws + 118489088ull);    // 4 KB [2][512]
    float* KNI = (float*)(ws + 118493184ull);    // 4 KB
    float* ATT = (float*)(ws + 118497280ull);    // 256 KB [2][8][64][64]

    // ---- d_out used as scratch until the final transpose ----
    u16*   R2 = (u16*)d_out;                     // 32 MB
    u16*   R3 = (u16*)d_out + 16777216;          // 32 MB
    float* Sp = (float*)((char*)d_out + 33554432ull); // 16 MB split-K partials

    const int BIG = 1 << 30;
    dim3 tb(32, 8);

    // prep
    transpose_k<<<dim3(512, 16, 2), tb, 0, stream>>>(x_in, XF, XBb, 512, 16384, 8388608, 8388608);
    transpose_k<<<dim3(16, 16, 2), tb, 0, stream>>>(Wq, nullptr, WQt, 512, 512, 262144, 262144);
    transpose_k<<<dim3(16, 16, 2), tb, 0, stream>>>(Wk, nullptr, WKt, 512, 512, 262144, 262144);
    transpose_k<<<dim3(16, 16, 2), tb, 0, stream>>>(Wv, nullptr, WVt, 512, 512, 262144, 262144);
    cvt_bf16_k<<<2048, 256, 0, stream>>>(w1, W1b);
    cvtw2_k<<<2048, 256, 0, stream>>>(w2, dw1, W2b);

    for (int l = 0; l < 2; l++) {
        // XT (bf16 [b][c][n]) into R2
        if (l == 0)
            cvt_bf16_k<<<16384, 256, 0, stream>>>(x_in, R2);
        else
            transpose16_k<<<dim3(16, 512, 2), tb, 0, stream>>>(XBb, R2, 16384, 512, 8388608, 8388608);
        // S = X^T X per batch: split-K partials
        gemm_nt_k<<<dim3(4, 8, 8), 256, 0, stream>>>(R2, R2, 16384, 16384, 512,
            512, 8388608, 2048, nullptr, nullptr, Sp, nullptr);
        sreduce_k<<<2048, 256, 0, stream>>>(Sp, Sbf);
        // T1 = S*Wq, T2 = S*Wk
        gemm_nt_k<<<dim3(4, 8), 256, 0, stream>>>(Sbf, WQt + l * 262144, 512, 512, 512,
            BIG, 0, 0, nullptr, nullptr, T1f, nullptr);
        gemm_nt_k<<<dim3(4, 8), 256, 0, stream>>>(Sbf, WKt + l * 262144, 512, 512, 512,
            BIG, 0, 0, nullptr, nullptr, T2f, nullptr);
        nrm_k<<<8, 256, 0, stream>>>(Wq + l * 262144, T1f, QNI);
        nrm_k<<<8, 256, 0, stream>>>(Wk + l * 262144, T2f, KNI);
        gsmall_k<<<dim3(8, 2), 256, 0, stream>>>(T2f, Wq + l * 262144, QNI, KNI,
            resc + l * 8, ATT);
        mbuild_k<<<dim3(8, 2), 256, 0, stream>>>(ATT, projW + l * 262144, Mnt);
        // V = x @ Wv
        gemm_nt_k<<<dim3(4, 256), 256, 0, stream>>>(XBb, WVt + l * 262144, 512, 512, 512,
            BIG, 0, 0, nullptr, nullptr, nullptr, R3);
        // x += V @ M^T + proj_b
        gemm_nt_k<<<dim3(4, 256), 256, 0, stream>>>(R3, Mnt, 512, 512, 512,
            16384, 262144, 0, projB + l * 512, XF, XF, nullptr);
        // positional branch: dwconv3+gelu -> R2, then dwconv3 accumulated into XF
        dwreg_k<3, 16, 4, true, false, false><<<dim3(64, 8, 2), 256, 0, stream>>>(
            R3, posw1 + l * 4608, R2, nullptr);
        dwreg_k<3, 16, 4, false, false, true><<<dim3(64, 8, 2), 256, 0, stream>>>(
            R2, posw2 + l * 4608, nullptr, XF);
        // PreNorm
        ln_k<<<8192, 256, 0, stream>>>(XF, lng + l * 512, lnb + l * 512, XBb);
        // MS-FFN, group-streamed (g0's 1x1 conv folded into W2b prescale)
        for (int g = 0; g < 4; g++) {
            gemm_nt_k<<<dim3(4, 256), 256, 0, stream>>>(XBb,
                W1b + l * 1048576 + g * 262144, 512, 512, 512,
                BIG, 0, 0, nullptr, nullptr, nullptr, R3);
            const u16* dsrc = R3;
            if (g == 1) {
                dwreg_k<3, 16, 4, false, true, false><<<dim3(64, 8, 2), 256, 0, stream>>>(
                    R3, dw3 + l * 4608, R2, nullptr);
                dsrc = R2;
            } else if (g == 2) {
                dwreg_k<5, 16, 2, false, true, false><<<dim3(128, 8, 2), 256, 0, stream>>>(
                    R3, dw5 + l * 12800, R2, nullptr);
                dsrc = R2;
            } else if (g == 3) {
                dwreg_k<7, 32, 2, false, true, false><<<dim3(128, 4, 2), 256, 0, stream>>>(
                    R3, dw7 + l * 25088, R2, nullptr);
                dsrc = R2;
            }
            gemm_nt_k<<<dim3(4, 256), 256, 0, stream>>>(dsrc,
                W2b + l * 1048576 + g * 512, 512, 2048, 512,
                BIG, 0, 0, nullptr, XF, XF, (g == 3) ? XBb : nullptr);
        }
    }
    // final: XF [b,n,c] -> out [b,c,n]
    transpose_k<<<dim3(16, 512, 2), tb, 0, stream>>>(XF, out, nullptr, 16384, 512, 8388608, 8388608);
}